// Round 9
// baseline (1555.572 us; speedup 1.0000x reference)
//
#include <hip/hip_runtime.h>

#define DEVI __device__ __forceinline__

typedef __attribute__((ext_vector_type(8))) short bf16x8;
typedef __attribute__((ext_vector_type(4))) float f32x4;
typedef __attribute__((ext_vector_type(4))) unsigned short usx4;

DEVI float bf2f(unsigned short u) {
  unsigned int b = ((unsigned int)u) << 16;
  float f;
  __builtin_memcpy(&f, &b, 4);
  return f;
}
DEVI unsigned short f2bf(float f) {
  unsigned int x;
  __builtin_memcpy(&x, &f, 4);
  x += 0x7FFFu + ((x >> 16) & 1u);
  return (unsigned short)(x >> 16);
}
DEVI void gload_lds16(const void* g, void* l) {
  __builtin_amdgcn_global_load_lds((const __attribute__((address_space(1))) void*)g,
                                   (__attribute__((address_space(3))) void*)l,
                                   16, 0, 0);
}
// fast gelu: tanh form, max |err| ~3e-4 (budget: absmax 0.031 @ thr 0.118)
DEVI float gelu_fast(float x) {
  const float u = 0.7978845608028654f * (x + 0.044715f * x * x * x);
  const float a = fabsf(u);
  const float e = __expf(-2.0f * a);
  float th = __fdividef(1.0f - e, 1.0f + e);
  th = u < 0.f ? -th : th;
  return 0.5f * x * (1.0f + th);
}

// ---------------------------------------------------------------------------
// Weight transpose + cast: W[K][N] fp32 -> Wt[N][K] bf16
// ---------------------------------------------------------------------------
__global__ __launch_bounds__(256) void wt_kernel(const float* __restrict__ W,
                                                 unsigned short* __restrict__ Wt,
                                                 int K, int N) {
  __shared__ float t[32][33];
  const int tx = threadIdx.x & 31, ty = threadIdx.x >> 5;  // 32 x 8
  const int n0 = blockIdx.x * 32, k0 = blockIdx.y * 32;
#pragma unroll
  for (int i = 0; i < 4; ++i)
    t[ty * 4 + i][tx] = W[(size_t)(k0 + ty * 4 + i) * N + n0 + tx];
  __syncthreads();
#pragma unroll
  for (int i = 0; i < 4; ++i)
    Wt[(size_t)(n0 + ty * 4 + i) * K + k0 + tx] = f2bf(t[tx][ty * 4 + i]);
}

// ---------------------------------------------------------------------------
// LayerNorm: x fp32 [rows][768] -> bf16 out. One wave per row.
// ---------------------------------------------------------------------------
__global__ __launch_bounds__(256) void ln_kernel(const float* __restrict__ x,
                                                 const float* __restrict__ w,
                                                 const float* __restrict__ b,
                                                 unsigned short* __restrict__ o) {
  const int lane = threadIdx.x & 63;
  const int wave = threadIdx.x >> 6;
  const size_t row = (size_t)blockIdx.x * 4 + wave;
  const float* xr = x + row * 768;
  float v[12];
  float s = 0.f, sq = 0.f;
#pragma unroll
  for (int i = 0; i < 3; ++i) {
    const float4 f = *(const float4*)&xr[i * 256 + lane * 4];
    v[i * 4 + 0] = f.x; v[i * 4 + 1] = f.y; v[i * 4 + 2] = f.z; v[i * 4 + 3] = f.w;
    s += f.x + f.y + f.z + f.w;
    sq += f.x * f.x + f.y * f.y + f.z * f.z + f.w * f.w;
  }
#pragma unroll
  for (int off = 32; off > 0; off >>= 1) {
    s += __shfl_xor(s, off);
    sq += __shfl_xor(sq, off);
  }
  const float mu = s * (1.f / 768.f);
  const float rs = rsqrtf(sq * (1.f / 768.f) - mu * mu + 1e-8f);
  unsigned short* orow = o + row * 768;
#pragma unroll
  for (int i = 0; i < 3; ++i) {
    usx4 st;
#pragma unroll
    for (int j = 0; j < 4; ++j) {
      const int c = i * 256 + lane * 4 + j;
      st[j] = f2bf((v[i * 4 + j] - mu) * rs * w[c] + b[c]);
    }
    *(usx4*)&orow[i * 256 + lane * 4] = st;
  }
}

// ---------------------------------------------------------------------------
// Fused residual + LayerNorm: x2 = x + y (y bf16); write x2 fp32 and LN(x2) bf16
// ---------------------------------------------------------------------------
__global__ __launch_bounds__(256) void fuse_kernel(const float* __restrict__ x,
                                                   const unsigned short* __restrict__ y,
                                                   const float* __restrict__ w,
                                                   const float* __restrict__ b,
                                                   float* __restrict__ x2,
                                                   unsigned short* __restrict__ o) {
  const int lane = threadIdx.x & 63;
  const int wave = threadIdx.x >> 6;
  const size_t row = (size_t)blockIdx.x * 4 + wave;
  const float* xr = x + row * 768;
  const unsigned short* yr = y + row * 768;
  float* x2r = x2 + row * 768;
  float v[12];
  float s = 0.f, sq = 0.f;
#pragma unroll
  for (int i = 0; i < 3; ++i) {
    const float4 f = *(const float4*)&xr[i * 256 + lane * 4];
    const usx4 yv = *(const usx4*)&yr[i * 256 + lane * 4];
    float t0 = f.x + bf2f(yv[0]);
    float t1 = f.y + bf2f(yv[1]);
    float t2 = f.z + bf2f(yv[2]);
    float t3 = f.w + bf2f(yv[3]);
    v[i * 4 + 0] = t0; v[i * 4 + 1] = t1; v[i * 4 + 2] = t2; v[i * 4 + 3] = t3;
    s += t0 + t1 + t2 + t3;
    sq += t0 * t0 + t1 * t1 + t2 * t2 + t3 * t3;
    float4 fo; fo.x = t0; fo.y = t1; fo.z = t2; fo.w = t3;
    *(float4*)&x2r[i * 256 + lane * 4] = fo;
  }
#pragma unroll
  for (int off = 32; off > 0; off >>= 1) {
    s += __shfl_xor(s, off);
    sq += __shfl_xor(sq, off);
  }
  const float mu = s * (1.f / 768.f);
  const float rs = rsqrtf(sq * (1.f / 768.f) - mu * mu + 1e-8f);
  unsigned short* orow = o + row * 768;
#pragma unroll
  for (int i = 0; i < 3; ++i) {
    usx4 st;
#pragma unroll
    for (int j = 0; j < 4; ++j) {
      const int c = i * 256 + lane * 4 + j;
      st[j] = f2bf((v[i * 4 + j] - mu) * rs * w[c] + b[c]);
    }
    *(usx4*)&orow[i * 256 + lane * 4] = st;
  }
}

// ---------------------------------------------------------------------------
// 128x256 bf16 MFMA GEMM. BK=32, 512 threads (8 waves, 2M x 4N, wave-tile
// 64x64), 72 KB LDS 3-slot ring -> 2 blocks/CU (launch_bounds(512,4)).
// 2-barrier loop + counted vmcnt(6) (2-tile issue-to-use slack > HBM lat).
// Involution chunk swizzle on 64B rows. MFMA operands SWAPPED (bF first):
// acc layout transposed -> lane holds 4 consecutive cols (j) of one row ->
// all epilogue stores vectorized (usx4 / float4), lines covered in a tight
// window (kills read-before-write fetch bloat).
// C = A[M,K] @ Bt[N,K]^T + bias. EPI 0: bf16 store; 1: gelu(fast) + store;
// 2: qkv split-store [bh][s][d] (elu+1 for q,k); 3: fp32 residual RMW
// (block order REVERSED for L3 LIFO handoff of hbuf).
// ---------------------------------------------------------------------------
template <int EPI>
__global__ __launch_bounds__(512, 4) void gemm_k(
    const unsigned short* __restrict__ A, const unsigned short* __restrict__ Bt,
    const float* __restrict__ bias, int N, int K,
    unsigned short* __restrict__ O0, unsigned short* __restrict__ O1,
    unsigned short* __restrict__ O2, float* __restrict__ OF) {
  __shared__ unsigned short sm[36864];  // A: 3x4096 @0, B: 3x8192 @12288
  const int tid = threadIdx.x;
  const int lane = tid & 63, wave = tid >> 6;
  const int wr = wave >> 2, wc = wave & 3;

  // T1: XCD-chunked block swizzle (nwg % 8 == 0 for all our grids)
  const int gx = gridDim.x;
  const int nwg = gx * gridDim.y;
  const int cpx = nwg >> 3;
  int wgid = blockIdx.x + gx * blockIdx.y;
  if (EPI == 3) wgid = nwg - 1 - wgid;  // LIFO: read hbuf tail-first (L3-hot)
  const int v = (wgid & 7) * cpx + (wgid >> 3);
  const size_t n0 = (size_t)(v % gx) * 256;
  const size_t m0 = (size_t)(v / gx) * 128;

  // staging: 64B rows = 4 chunks of 16B. phys chunk pc at row r holds logical
  // chunk c = pc ^ f(r), f(r) = (r ^ (r>>2)) & 3 (involution both sides).
  const int rA = tid >> 2;                       // 0..127
  const int cA = (tid & 3) ^ ((rA ^ (rA >> 2)) & 3);
  const unsigned short* srcA = A + (m0 + rA) * (size_t)K + cA * 8;
  const unsigned short* srcB0 = Bt + (n0 + rA) * (size_t)K + cA * 8;
  const unsigned short* srcB1 = srcB0 + (size_t)128 * K;  // f(r+128)==f(r)

  unsigned short* smA = sm;
  unsigned short* smB = sm + 12288;

  f32x4 acc[4][4];
#pragma unroll
  for (int m = 0; m < 4; ++m)
#pragma unroll
    for (int n = 0; n < 4; ++n) acc[m][n] = f32x4{0.f, 0.f, 0.f, 0.f};

  // fragment reads: row = (w*64 + m*16 + L) -> f(row) = fL (indep of m, w)
  const int L = lane & 15, kc4 = lane >> 4;
  const int fL = (L ^ (L >> 2)) & 3;
  const int aoff = (wr * 64 + L) * 32 + ((kc4 ^ fL) << 3);
  const int boff = (wc * 64 + L) * 32 + ((kc4 ^ fL) << 3);

  const int nt = K >> 5;

#define STAGE(tt)                                               \
  do {                                                          \
    const int p_ = (tt) % 3;                                    \
    const size_t ko_ = (size_t)(tt) * 32;                       \
    gload_lds16(srcA + ko_, smA + p_ * 4096 + tid * 8);         \
    gload_lds16(srcB0 + ko_, smB + p_ * 8192 + tid * 8);        \
    gload_lds16(srcB1 + ko_, smB + p_ * 8192 + 4096 + tid * 8); \
  } while (0)

  STAGE(0);
  STAGE(1);
  STAGE(2);

  for (int t = 0; t < nt; ++t) {
    const int rem = nt - t;
    if (rem > 2)
      asm volatile("s_waitcnt vmcnt(6)" ::: "memory");
    else if (rem == 2)
      asm volatile("s_waitcnt vmcnt(3)" ::: "memory");
    else
      asm volatile("s_waitcnt vmcnt(0)" ::: "memory");
    __builtin_amdgcn_s_barrier();  // slot t%3 fully staged by all waves
    const unsigned short* Abase = smA + (t % 3) * 4096 + aoff;
    const unsigned short* Bbase = smB + (t % 3) * 8192 + boff;
    bf16x8 aF[4], bF[4];
#pragma unroll
    for (int m = 0; m < 4; ++m) aF[m] = *(const bf16x8*)(Abase + m * 512);
#pragma unroll
    for (int n = 0; n < 4; ++n) bF[n] = *(const bf16x8*)(Bbase + n * 512);
    asm volatile("s_waitcnt lgkmcnt(0)" ::: "memory");
    __builtin_amdgcn_s_barrier();  // all waves' reads of slot t%3 drained
    if (t + 3 < nt) STAGE(t + 3);  // safe to overwrite slot t%3
    __builtin_amdgcn_s_setprio(1);
#pragma unroll
    for (int m = 0; m < 4; ++m)
#pragma unroll
      for (int n = 0; n < 4; ++n)
        acc[m][n] = __builtin_amdgcn_mfma_f32_16x16x32_bf16(bF[n], aF[m], acc[m][n], 0, 0, 0);
    __builtin_amdgcn_s_setprio(0);
  }
#undef STAGE

  // transposed acc: for tile (m,n): row = m*16 + (lane&15),
  // cols = n*16 + (lane>>4)*4 + j  (4 consecutive cols per lane)
  const int cl = lane & 15;
  const int cg = (lane >> 4) * 4;

  if (EPI == 2) {
    // qkv: wave's 64x64 region is one (tsec, h) section; store [bh][s][d].
    const int cbase = (int)n0 + wc * 64;
    const int tsec = cbase / 768;
    const int h = (cbase - tsec * 768) >> 6;
    const int rbase = (int)m0 + wr * 64;
    const int b = rbase >> 12;
    const int s0w = rbase & 4095;
    const size_t bh = (size_t)b * 12 + h;
    unsigned short* dst = (tsec == 0) ? O0 : (tsec == 1 ? O1 : O2);
#pragma unroll
    for (int m = 0; m < 4; ++m) {
      const size_t s = (size_t)(s0w + m * 16 + cl);
#pragma unroll
      for (int n = 0; n < 4; ++n) {
        const int d0 = n * 16 + cg;
        const float4 bv = *(const float4*)&bias[cbase + d0];
        usx4 st;
#pragma unroll
        for (int j = 0; j < 4; ++j) {
          float val = acc[m][n][j] + ((const float*)&bv)[j];
          if (tsec < 2) val = val > 0.f ? val + 1.f : __expf(val);
          st[j] = f2bf(val);
        }
        *(usx4*)&dst[(bh * 4096 + s) * 64 + d0] = st;
      }
    }
    return;
  }

  // common epilogue (EPI 0, 1, 3)
#pragma unroll
  for (int m = 0; m < 4; ++m) {
    const size_t r = m0 + wr * 64 + m * 16 + cl;
#pragma unroll
    for (int n = 0; n < 4; ++n) {
      const size_t c = n0 + wc * 64 + n * 16 + cg;
      const float4 bv = *(const float4*)&bias[c];
      if (EPI == 0) {
        usx4 st;
#pragma unroll
        for (int j = 0; j < 4; ++j) st[j] = f2bf(acc[m][n][j] + ((const float*)&bv)[j]);
        *(usx4*)&O0[r * (size_t)N + c] = st;
      } else if (EPI == 1) {
        usx4 st;
#pragma unroll
        for (int j = 0; j < 4; ++j)
          st[j] = f2bf(gelu_fast(acc[m][n][j] + ((const float*)&bv)[j]));
        *(usx4*)&O0[r * (size_t)N + c] = st;
      } else {  // EPI == 3: residual RMW into fp32 out, vectorized 16B
        float4 o = *(const float4*)&OF[r * (size_t)N + c];
        o.x += acc[m][n][0] + bv.x;
        o.y += acc[m][n][1] + bv.y;
        o.z += acc[m][n][2] + bv.z;
        o.w += acc[m][n][3] + bv.w;
        *(float4*)&OF[r * (size_t)N + c] = o;
      }
    }
  }
}

// ---------------------------------------------------------------------------
// kv + ksum fused. k,v are [bh][s][d] bf16 (d=64, s=4096).
// Per bh: stage 128-s tiles transposed+swizzled into LDS, MFMA kv[d][e],
// accumulate ksum[d]. Writes kvT[bh][e][d] fp32 and ksum[bh][d].
// Block order reversed (LIFO handoff of k/v from qkv).
// ---------------------------------------------------------------------------
__global__ __launch_bounds__(256) void kv_kernel(const unsigned short* __restrict__ k,
                                                 const unsigned short* __restrict__ v,
                                                 float* __restrict__ kvT,
                                                 float* __restrict__ ksum) {
  __shared__ unsigned short kl[8192];  // 16 KB
  __shared__ unsigned short vl[8192];  // 16 KB
  __shared__ float red[256];
  const int tid = threadIdx.x, lane = tid & 63, wave = tid >> 6;
  const size_t bh = (size_t)(gridDim.x - 1 - blockIdx.x);
  const unsigned short* kb = k + bh * (size_t)(4096 * 64);
  const unsigned short* vb = v + bh * (size_t)(4096 * 64);
  f32x4 acc[4];
#pragma unroll
  for (int n = 0; n < 4; ++n) acc[n] = f32x4{0.f, 0.f, 0.f, 0.f};
  float ks = 0.f;

  const int r = tid >> 1;       // s-row 0..127
  const int hf = tid & 1;       // d half
  const int c4 = r >> 5;        // s>>5 quarter
  const int scw = (r >> 3) & 3; // write sub-chunk
  int wofs[4];
#pragma unroll
  for (int dd = 0; dd < 4; ++dd)
    wofs[dd] = c4 * 32 + ((scw ^ ((c4 ^ dd) & 3)) << 3) + (r & 7);

  const int L = lane & 15, kc4 = lane >> 4;
  const int dA = wave * 16 + L;
  const int dq = tid & 63, q4 = tid >> 6;
  const int Fks = (q4 ^ dq) & 3;
  const int ksbase = (dq * 4 + q4) * 32;

  for (int st = 0; st < 32; ++st) {
    const int s0 = st * 128;
    __syncthreads();  // prior tile's reads done before overwrite
    {
      const unsigned short* krow = kb + (size_t)(s0 + r) * 64 + hf * 32;
      const unsigned short* vrow = vb + (size_t)(s0 + r) * 64 + hf * 32;
      bf16x8 kk[4], vv[4];
#pragma unroll
      for (int g = 0; g < 4; ++g) {
        kk[g] = *(const bf16x8*)(krow + g * 8);
        vv[g] = *(const bf16x8*)(vrow + g * 8);
      }
#pragma unroll
      for (int g = 0; g < 4; ++g)
#pragma unroll
        for (int i = 0; i < 8; ++i) {
          const int d = hf * 32 + g * 8 + i;
          const int a = d * 128 + wofs[d & 3];
          kl[a] = (unsigned short)kk[g][i];
          vl[a] = (unsigned short)vv[g][i];
        }
    }
    __syncthreads();
    // ksum partial
#pragma unroll
    for (int scc = 0; scc < 4; ++scc) {
      const bf16x8 t8 = *(const bf16x8*)&kl[ksbase + ((scc ^ Fks) << 3)];
#pragma unroll
      for (int i = 0; i < 8; ++i) ks += bf2f((unsigned short)t8[i]);
    }
    // MFMA: D[d][e] += sum_s k[s,d] v[s,e]
#pragma unroll
    for (int ksl = 0; ksl < 4; ++ksl) {
      const int physA = kc4 ^ ((ksl ^ dA) & 3);
      const bf16x8 aF = *(const bf16x8*)&kl[(dA * 4 + ksl) * 32 + physA * 8];
#pragma unroll
      for (int n = 0; n < 4; ++n) {
        const int e = n * 16 + L;
        const int physB = kc4 ^ ((ksl ^ e) & 3);
        const bf16x8 bF = *(const bf16x8*)&vl[(e * 4 + ksl) * 32 + physB * 8];
        acc[n] = __builtin_amdgcn_mfma_f32_16x16x32_bf16(aF, bF, acc[n], 0, 0, 0);
      }
    }
  }
  red[tid] = ks;
  __syncthreads();
  if (tid < 64) ksum[bh * 64 + tid] = red[tid] + red[64 + tid] + red[128 + tid] + red[192 + tid];
#pragma unroll
  for (int n = 0; n < 4; ++n)
#pragma unroll
    for (int j = 0; j < 4; ++j) {
      const int d = wave * 16 + (lane >> 4) * 4 + j;
      const int e = n * 16 + (lane & 15);
      kvT[bh * 4096 + e * 64 + d] = acc[n][j];
    }
}

// ---------------------------------------------------------------------------
// attn out: out[s,e] = z_s * sum_d q[s,d] kv[d,e]; z_s = 1/sum_d q[s,d] ksum[d]
// Block order reversed (LIFO handoff of q).
// ---------------------------------------------------------------------------
__global__ __launch_bounds__(256) void attn_out_kernel(const unsigned short* __restrict__ q,
                                                       const float* __restrict__ kvT,
                                                       const float* __restrict__ ksum,
                                                       unsigned short* __restrict__ attnout) {
  __shared__ float kvl[4096];
  __shared__ float ksl[64];
  __shared__ float zl[4 * 64];
  const int tid = threadIdx.x;
  const int lane = tid & 63, wave = tid >> 6;
  const int bidx = gridDim.x - 1 - blockIdx.x;
  const int bh = bidx >> 2;
  const int chunk = bidx & 3;
  const int b = bh / 12, h = bh % 12;
  const float* kvb = kvT + (size_t)bh * 4096;
  for (int i = tid; i < 4096; i += 256) kvl[i] = kvb[i];
  if (tid < 64) ksl[tid] = ksum[(size_t)bh * 64 + tid];
  __syncthreads();

  const int kh = (lane >> 4) * 8;
  bf16x8 bF[4], ksF;
#pragma unroll
  for (int n = 0; n < 4; ++n) {
    bf16x8 t;
#pragma unroll
    for (int j = 0; j < 8; ++j)
      t[j] = (short)f2bf(kvl[((lane & 15) + 16 * n) * 64 + kh + j]);
    bF[n] = t;
  }
  {
    bf16x8 t;
#pragma unroll
    for (int j = 0; j < 8; ++j)
      t[j] = ((lane & 15) == 0) ? (short)f2bf(ksl[kh + j]) : (short)0;
    ksF = t;
  }
  const unsigned short* qb = q + (size_t)bh * 4096 * 64;

  for (int st = 0; st < 4; ++st) {
    const int s0 = chunk * 1024 + wave * 256 + st * 64;
    bf16x8 aF[4];
#pragma unroll
    for (int m = 0; m < 4; ++m)
      aF[m] = *(const bf16x8*)&qb[(size_t)(s0 + (lane & 15) + 16 * m) * 64 + kh];
    f32x4 acc[4][4];
    f32x4 dacc[4];
#pragma unroll
    for (int m = 0; m < 4; ++m) {
      dacc[m] = f32x4{0.f, 0.f, 0.f, 0.f};
#pragma unroll
      for (int n = 0; n < 4; ++n) acc[m][n] = f32x4{0.f, 0.f, 0.f, 0.f};
    }
#pragma unroll
    for (int m = 0; m < 4; ++m) {
#pragma unroll
      for (int n = 0; n < 4; ++n)
        acc[m][n] = __builtin_amdgcn_mfma_f32_16x16x32_bf16(aF[m], bF[n], acc[m][n], 0, 0, 0);
      dacc[m] = __builtin_amdgcn_mfma_f32_16x16x32_bf16(aF[m], ksF, dacc[m], 0, 0, 0);
    }
    if ((lane & 15) == 0) {
#pragma unroll
      for (int m = 0; m < 4; ++m)
#pragma unroll
        for (int j = 0; j < 4; ++j)
          zl[wave * 64 + m * 16 + (lane >> 4) * 4 + j] = 1.0f / dacc[m][j];
    }
    __syncthreads();
#pragma unroll
    for (int m = 0; m < 4; ++m)
#pragma unroll
      for (int n = 0; n < 4; ++n)
#pragma unroll
        for (int j = 0; j < 4; ++j) {
          const int sl = m * 16 + (lane >> 4) * 4 + j;
          const int s = s0 + sl;
          const float val = acc[m][n][j] * zl[wave * 64 + sl];
          const int e = n * 16 + (lane & 15);
          attnout[((size_t)b * 4096 + s) * 768 + h * 64 + e] = f2bf(val);
        }
    __syncthreads();
  }
}

// ---------------------------------------------------------------------------
extern "C" void kernel_launch(void* const* d_in, const int* in_sizes, int n_in,
                              void* d_out, int out_size, void* d_ws, size_t ws_size,
                              hipStream_t stream) {
  const float* x = (const float*)d_in[0];
  const float* qkv_w = (const float*)d_in[1];
  const float* qkv_b = (const float*)d_in[2];
  const float* proj_w = (const float*)d_in[3];
  const float* proj_b = (const float*)d_in[4];
  const float* fc1_w = (const float*)d_in[5];
  const float* fc1_b = (const float*)d_in[6];
  const float* fc2_w = (const float*)d_in[7];
  const float* fc2_b = (const float*)d_in[8];
  const float* ln1_w = (const float*)d_in[9];
  const float* ln1_b = (const float*)d_in[10];
  const float* ln2_w = (const float*)d_in[11];
  const float* ln2_b = (const float*)d_in[12];
  float* out = (float*)d_out;

  char* ws = (char*)d_ws;
  const size_t PL = (size_t)65536 * 768 * 2;  // one bf16 plane
  unsigned short* xn = (unsigned short*)(ws + 0 * PL);
  unsigned short* q = (unsigned short*)(ws + 1 * PL);
  unsigned short* kbuf = (unsigned short*)(ws + 2 * PL);
  unsigned short* vbuf = (unsigned short*)(ws + 3 * PL);
  unsigned short* attnout = xn;
  unsigned short* ybuf = kbuf;
  unsigned short* xn2 = (unsigned short*)(ws + 4 * PL);
  unsigned short* hbuf = (unsigned short*)(ws + 0 * PL);  // planes 0-3
  size_t off = 5 * PL;
  float* kvT = (float*)(ws + off); off += (size_t)192 * 4096 * 4;
  float* ksum = (float*)(ws + off); off += (size_t)192 * 64 * 4;
  unsigned short* qkvWt = (unsigned short*)(ws + off); off += (size_t)2304 * 768 * 2;
  unsigned short* projWt = (unsigned short*)(ws + off); off += (size_t)768 * 768 * 2;
  unsigned short* fc1Wt = (unsigned short*)(ws + off); off += (size_t)3072 * 768 * 2;
  unsigned short* fc2Wt = (unsigned short*)(ws + off); off += (size_t)768 * 3072 * 2;

  // 1. weight transpose+cast
  wt_kernel<<<dim3(72, 24), 256, 0, stream>>>(qkv_w, qkvWt, 768, 2304);
  wt_kernel<<<dim3(24, 24), 256, 0, stream>>>(proj_w, projWt, 768, 768);
  wt_kernel<<<dim3(96, 24), 256, 0, stream>>>(fc1_w, fc1Wt, 768, 3072);
  wt_kernel<<<dim3(24, 96), 256, 0, stream>>>(fc2_w, fc2Wt, 3072, 768);
  // 2. LN1
  ln_kernel<<<16384, 256, 0, stream>>>(x, ln1_w, ln1_b, xn);
  // 3. qkv GEMM: q,k (elu+1), v all stored [bh][s][d]
  gemm_k<2><<<dim3(9, 512), 512, 0, stream>>>(xn, qkvWt, qkv_b, 2304, 768, q, kbuf, vbuf, nullptr);
  // 4. kv + ksum (transpose inside)
  kv_kernel<<<192, 256, 0, stream>>>(kbuf, vbuf, kvT, ksum);
  // 5. attention out
  attn_out_kernel<<<768, 256, 0, stream>>>(q, kvT, ksum, attnout);
  // 6. proj GEMM -> y
  gemm_k<0><<<dim3(3, 512), 512, 0, stream>>>(attnout, projWt, proj_b, 768, 768, ybuf, nullptr,
                                              nullptr, nullptr);
  // 7. residual + LN2 (x2 lives in d_out)
  fuse_kernel<<<16384, 256, 0, stream>>>(x, ybuf, ln2_w, ln2_b, out, xn2);
  // 8. fc1 + gelu (fast tanh-form)
  gemm_k<1><<<dim3(12, 512), 512, 0, stream>>>(xn2, fc1Wt, fc1_b, 3072, 768, hbuf, nullptr,
                                               nullptr, nullptr);
  // 9. fc2 + residual RMW into out (reversed block order)
  gemm_k<3><<<dim3(3, 512), 512, 0, stream>>>(hbuf, fc2Wt, fc2_b, 768, 3072, nullptr, nullptr,
                                              nullptr, out);
  (void)in_sizes; (void)n_in; (void)out_size; (void)ws_size;
}

// Round 10
// 1517.488 us; speedup vs baseline: 1.0251x; 1.0251x over previous
//
#include <hip/hip_runtime.h>

#define DEVI __device__ __forceinline__

typedef __attribute__((ext_vector_type(8))) short bf16x8;
typedef __attribute__((ext_vector_type(4))) float f32x4;
typedef __attribute__((ext_vector_type(4))) unsigned short usx4;

DEVI float bf2f(unsigned short u) {
  unsigned int b = ((unsigned int)u) << 16;
  float f;
  __builtin_memcpy(&f, &b, 4);
  return f;
}
DEVI unsigned short f2bf(float f) {
  unsigned int x;
  __builtin_memcpy(&x, &f, 4);
  x += 0x7FFFu + ((x >> 16) & 1u);
  return (unsigned short)(x >> 16);
}
DEVI void gload_lds16(const void* g, void* l) {
  __builtin_amdgcn_global_load_lds((const __attribute__((address_space(1))) void*)g,
                                   (__attribute__((address_space(3))) void*)l,
                                   16, 0, 0);
}
// fast gelu: tanh form, max |err| ~3e-4 (budget: absmax 0.031 @ thr 0.118)
DEVI float gelu_fast(float x) {
  const float u = 0.7978845608028654f * (x + 0.044715f * x * x * x);
  const float a = fabsf(u);
  const float e = __expf(-2.0f * a);
  float th = __fdividef(1.0f - e, 1.0f + e);
  th = u < 0.f ? -th : th;
  return 0.5f * x * (1.0f + th);
}

// ---------------------------------------------------------------------------
// Weight transpose + cast: W[K][N] fp32 -> Wt[N][K] bf16
// ---------------------------------------------------------------------------
__global__ __launch_bounds__(256) void wt_kernel(const float* __restrict__ W,
                                                 unsigned short* __restrict__ Wt,
                                                 int K, int N) {
  __shared__ float t[32][33];
  const int tx = threadIdx.x & 31, ty = threadIdx.x >> 5;  // 32 x 8
  const int n0 = blockIdx.x * 32, k0 = blockIdx.y * 32;
#pragma unroll
  for (int i = 0; i < 4; ++i)
    t[ty * 4 + i][tx] = W[(size_t)(k0 + ty * 4 + i) * N + n0 + tx];
  __syncthreads();
#pragma unroll
  for (int i = 0; i < 4; ++i)
    Wt[(size_t)(n0 + ty * 4 + i) * K + k0 + tx] = f2bf(t[tx][ty * 4 + i]);
}

// ---------------------------------------------------------------------------
// LayerNorm: x fp32 [rows][768] -> bf16 out. One wave per row.
// ---------------------------------------------------------------------------
__global__ __launch_bounds__(256) void ln_kernel(const float* __restrict__ x,
                                                 const float* __restrict__ w,
                                                 const float* __restrict__ b,
                                                 unsigned short* __restrict__ o) {
  const int lane = threadIdx.x & 63;
  const int wave = threadIdx.x >> 6;
  const size_t row = (size_t)blockIdx.x * 4 + wave;
  const float* xr = x + row * 768;
  float v[12];
  float s = 0.f, sq = 0.f;
#pragma unroll
  for (int i = 0; i < 3; ++i) {
    const float4 f = *(const float4*)&xr[i * 256 + lane * 4];
    v[i * 4 + 0] = f.x; v[i * 4 + 1] = f.y; v[i * 4 + 2] = f.z; v[i * 4 + 3] = f.w;
    s += f.x + f.y + f.z + f.w;
    sq += f.x * f.x + f.y * f.y + f.z * f.z + f.w * f.w;
  }
#pragma unroll
  for (int off = 32; off > 0; off >>= 1) {
    s += __shfl_xor(s, off);
    sq += __shfl_xor(sq, off);
  }
  const float mu = s * (1.f / 768.f);
  const float rs = rsqrtf(sq * (1.f / 768.f) - mu * mu + 1e-8f);
  unsigned short* orow = o + row * 768;
#pragma unroll
  for (int i = 0; i < 3; ++i) {
    usx4 st;
#pragma unroll
    for (int j = 0; j < 4; ++j) {
      const int c = i * 256 + lane * 4 + j;
      st[j] = f2bf((v[i * 4 + j] - mu) * rs * w[c] + b[c]);
    }
    *(usx4*)&orow[i * 256 + lane * 4] = st;
  }
}

// ---------------------------------------------------------------------------
// Fused residual + LayerNorm: x2 = x + y (y bf16); write x2 fp32 and LN(x2) bf16
// ---------------------------------------------------------------------------
__global__ __launch_bounds__(256) void fuse_kernel(const float* __restrict__ x,
                                                   const unsigned short* __restrict__ y,
                                                   const float* __restrict__ w,
                                                   const float* __restrict__ b,
                                                   float* __restrict__ x2,
                                                   unsigned short* __restrict__ o) {
  const int lane = threadIdx.x & 63;
  const int wave = threadIdx.x >> 6;
  const size_t row = (size_t)blockIdx.x * 4 + wave;
  const float* xr = x + row * 768;
  const unsigned short* yr = y + row * 768;
  float* x2r = x2 + row * 768;
  float v[12];
  float s = 0.f, sq = 0.f;
#pragma unroll
  for (int i = 0; i < 3; ++i) {
    const float4 f = *(const float4*)&xr[i * 256 + lane * 4];
    const usx4 yv = *(const usx4*)&yr[i * 256 + lane * 4];
    float t0 = f.x + bf2f(yv[0]);
    float t1 = f.y + bf2f(yv[1]);
    float t2 = f.z + bf2f(yv[2]);
    float t3 = f.w + bf2f(yv[3]);
    v[i * 4 + 0] = t0; v[i * 4 + 1] = t1; v[i * 4 + 2] = t2; v[i * 4 + 3] = t3;
    s += t0 + t1 + t2 + t3;
    sq += t0 * t0 + t1 * t1 + t2 * t2 + t3 * t3;
    float4 fo; fo.x = t0; fo.y = t1; fo.z = t2; fo.w = t3;
    *(float4*)&x2r[i * 256 + lane * 4] = fo;
  }
#pragma unroll
  for (int off = 32; off > 0; off >>= 1) {
    s += __shfl_xor(s, off);
    sq += __shfl_xor(sq, off);
  }
  const float mu = s * (1.f / 768.f);
  const float rs = rsqrtf(sq * (1.f / 768.f) - mu * mu + 1e-8f);
  unsigned short* orow = o + row * 768;
#pragma unroll
  for (int i = 0; i < 3; ++i) {
    usx4 st;
#pragma unroll
    for (int j = 0; j < 4; ++j) {
      const int c = i * 256 + lane * 4 + j;
      st[j] = f2bf((v[i * 4 + j] - mu) * rs * w[c] + b[c]);
    }
    *(usx4*)&orow[i * 256 + lane * 4] = st;
  }
}

// ---------------------------------------------------------------------------
// 128x256 bf16 MFMA GEMM. BK=32, 512 threads (8 waves, 2M x 4N, wave-tile
// 64x64), 72 KB LDS 3-slot ring -> 2 blocks/CU (launch_bounds(512,4)).
// SINGLE-BARRIER loop: {vmcnt(3) -> barrier -> STAGE(t+2) -> ds_read ->
// lgkmcnt(0) -> setprio MFMA}. Safety: each wave drains its own lgkm before
// its MFMAs, hence before the NEXT barrier; the stage after barrier t targets
// slot (t+2)%3 = (t-1)%3 whose readers all drained before barrier t.
// Involution chunk swizzle on 64B rows. MFMA operands swapped (bF first) ->
// transposed acc -> vectorized epilogue stores.
// C = A[M,K] @ Bt[N,K]^T + bias. EPI 0: bf16 store; 1: gelu(fast) + store;
// 2: qkv split-store [bh][s][d] (elu+1 for q,k); 3: fp32 residual RMW (LIFO).
// ---------------------------------------------------------------------------
template <int EPI>
__global__ __launch_bounds__(512, 4) void gemm_k(
    const unsigned short* __restrict__ A, const unsigned short* __restrict__ Bt,
    const float* __restrict__ bias, int N, int K,
    unsigned short* __restrict__ O0, unsigned short* __restrict__ O1,
    unsigned short* __restrict__ O2, float* __restrict__ OF) {
  __shared__ unsigned short sm[36864];  // A: 3x4096 @0, B: 3x8192 @12288
  const int tid = threadIdx.x;
  const int lane = tid & 63, wave = tid >> 6;
  const int wr = wave >> 2, wc = wave & 3;

  // T1: XCD-chunked block swizzle (nwg % 8 == 0 for all our grids)
  const int gx = gridDim.x;
  const int nwg = gx * gridDim.y;
  const int cpx = nwg >> 3;
  int wgid = blockIdx.x + gx * blockIdx.y;
  if (EPI == 3) wgid = nwg - 1 - wgid;  // LIFO: read hbuf tail-first (L3-hot)
  const int v = (wgid & 7) * cpx + (wgid >> 3);
  const size_t n0 = (size_t)(v % gx) * 256;
  const size_t m0 = (size_t)(v / gx) * 128;

  // staging: 64B rows = 4 chunks of 16B. phys chunk pc at row r holds logical
  // chunk c = pc ^ f(r), f(r) = (r ^ (r>>2)) & 3 (involution both sides).
  const int rA = tid >> 2;                       // 0..127
  const int cA = (tid & 3) ^ ((rA ^ (rA >> 2)) & 3);
  const unsigned short* srcA = A + (m0 + rA) * (size_t)K + cA * 8;
  const unsigned short* srcB0 = Bt + (n0 + rA) * (size_t)K + cA * 8;
  const unsigned short* srcB1 = srcB0 + (size_t)128 * K;  // f(r+128)==f(r)

  unsigned short* smA = sm;
  unsigned short* smB = sm + 12288;

  f32x4 acc[4][4];
#pragma unroll
  for (int m = 0; m < 4; ++m)
#pragma unroll
    for (int n = 0; n < 4; ++n) acc[m][n] = f32x4{0.f, 0.f, 0.f, 0.f};

  // fragment reads: row = (w*64 + m*16 + L) -> f(row) = fL (indep of m, w)
  const int L = lane & 15, kc4 = lane >> 4;
  const int fL = (L ^ (L >> 2)) & 3;
  const int aoff = (wr * 64 + L) * 32 + ((kc4 ^ fL) << 3);
  const int boff = (wc * 64 + L) * 32 + ((kc4 ^ fL) << 3);

  const int nt = K >> 5;

#define STAGE(tt)                                               \
  do {                                                          \
    const int p_ = (tt) % 3;                                    \
    const size_t ko_ = (size_t)(tt) * 32;                       \
    gload_lds16(srcA + ko_, smA + p_ * 4096 + tid * 8);         \
    gload_lds16(srcB0 + ko_, smB + p_ * 8192 + tid * 8);        \
    gload_lds16(srcB1 + ko_, smB + p_ * 8192 + 4096 + tid * 8); \
  } while (0)

  STAGE(0);
  STAGE(1);

  for (int t = 0; t < nt; ++t) {
    if (t + 1 < nt)
      asm volatile("s_waitcnt vmcnt(3)" ::: "memory");  // slot t%3 landed
    else
      asm volatile("s_waitcnt vmcnt(0)" ::: "memory");
    __builtin_amdgcn_s_barrier();  // slot t ready everywhere; reads of slot
                                   // (t-1)%3 drained by every wave
    if (t + 2 < nt) STAGE(t + 2);  // targets slot (t+2)%3 == (t-1)%3: safe
    const unsigned short* Abase = smA + (t % 3) * 4096 + aoff;
    const unsigned short* Bbase = smB + (t % 3) * 8192 + boff;
    bf16x8 aF[4], bF[4];
#pragma unroll
    for (int m = 0; m < 4; ++m) aF[m] = *(const bf16x8*)(Abase + m * 512);
#pragma unroll
    for (int n = 0; n < 4; ++n) bF[n] = *(const bf16x8*)(Bbase + n * 512);
    asm volatile("s_waitcnt lgkmcnt(0)" ::: "memory");
    __builtin_amdgcn_sched_barrier(0);
    __builtin_amdgcn_s_setprio(1);
#pragma unroll
    for (int m = 0; m < 4; ++m)
#pragma unroll
      for (int n = 0; n < 4; ++n)
        acc[m][n] = __builtin_amdgcn_mfma_f32_16x16x32_bf16(bF[n], aF[m], acc[m][n], 0, 0, 0);
    __builtin_amdgcn_s_setprio(0);
  }
#undef STAGE

  // transposed acc: for tile (m,n): row = m*16 + (lane&15),
  // cols = n*16 + (lane>>4)*4 + j  (4 consecutive cols per lane)
  const int cl = lane & 15;
  const int cg = (lane >> 4) * 4;

  if (EPI == 2) {
    // qkv: wave's 64x64 region is one (tsec, h) section; store [bh][s][d].
    const int cbase = (int)n0 + wc * 64;
    const int tsec = cbase / 768;
    const int h = (cbase - tsec * 768) >> 6;
    const int rbase = (int)m0 + wr * 64;
    const int b = rbase >> 12;
    const int s0w = rbase & 4095;
    const size_t bh = (size_t)b * 12 + h;
    unsigned short* dst = (tsec == 0) ? O0 : (tsec == 1 ? O1 : O2);
#pragma unroll
    for (int m = 0; m < 4; ++m) {
      const size_t s = (size_t)(s0w + m * 16 + cl);
#pragma unroll
      for (int n = 0; n < 4; ++n) {
        const int d0 = n * 16 + cg;
        const float4 bv = *(const float4*)&bias[cbase + d0];
        usx4 st;
#pragma unroll
        for (int j = 0; j < 4; ++j) {
          float val = acc[m][n][j] + ((const float*)&bv)[j];
          if (tsec < 2) val = val > 0.f ? val + 1.f : __expf(val);
          st[j] = f2bf(val);
        }
        *(usx4*)&dst[(bh * 4096 + s) * 64 + d0] = st;
      }
    }
    return;
  }

  // common epilogue (EPI 0, 1, 3)
#pragma unroll
  for (int m = 0; m < 4; ++m) {
    const size_t r = m0 + wr * 64 + m * 16 + cl;
#pragma unroll
    for (int n = 0; n < 4; ++n) {
      const size_t c = n0 + wc * 64 + n * 16 + cg;
      const float4 bv = *(const float4*)&bias[c];
      if (EPI == 0) {
        usx4 st;
#pragma unroll
        for (int j = 0; j < 4; ++j) st[j] = f2bf(acc[m][n][j] + ((const float*)&bv)[j]);
        *(usx4*)&O0[r * (size_t)N + c] = st;
      } else if (EPI == 1) {
        usx4 st;
#pragma unroll
        for (int j = 0; j < 4; ++j)
          st[j] = f2bf(gelu_fast(acc[m][n][j] + ((const float*)&bv)[j]));
        *(usx4*)&O0[r * (size_t)N + c] = st;
      } else {  // EPI == 3: residual RMW into fp32 out, vectorized 16B
        float4 o = *(const float4*)&OF[r * (size_t)N + c];
        o.x += acc[m][n][0] + bv.x;
        o.y += acc[m][n][1] + bv.y;
        o.z += acc[m][n][2] + bv.z;
        o.w += acc[m][n][3] + bv.w;
        *(float4*)&OF[r * (size_t)N + c] = o;
      }
    }
  }
}

// ---------------------------------------------------------------------------
// kv + ksum fused. k,v are [bh][s][d] bf16 (d=64, s=4096).
// Per bh: stage 128-s tiles transposed+swizzled into LDS, MFMA kv[d][e],
// accumulate ksum[d]. Writes kvT[bh][e][d] fp32 and ksum[bh][d].
// Block order reversed (LIFO handoff of k/v from qkv).
// ---------------------------------------------------------------------------
__global__ __launch_bounds__(256) void kv_kernel(const unsigned short* __restrict__ k,
                                                 const unsigned short* __restrict__ v,
                                                 float* __restrict__ kvT,
                                                 float* __restrict__ ksum) {
  __shared__ unsigned short kl[8192];  // 16 KB
  __shared__ unsigned short vl[8192];  // 16 KB
  __shared__ float red[256];
  const int tid = threadIdx.x, lane = tid & 63, wave = tid >> 6;
  const size_t bh = (size_t)(gridDim.x - 1 - blockIdx.x);
  const unsigned short* kb = k + bh * (size_t)(4096 * 64);
  const unsigned short* vb = v + bh * (size_t)(4096 * 64);
  f32x4 acc[4];
#pragma unroll
  for (int n = 0; n < 4; ++n) acc[n] = f32x4{0.f, 0.f, 0.f, 0.f};
  float ks = 0.f;

  const int r = tid >> 1;       // s-row 0..127
  const int hf = tid & 1;       // d half
  const int c4 = r >> 5;        // s>>5 quarter
  const int scw = (r >> 3) & 3; // write sub-chunk
  int wofs[4];
#pragma unroll
  for (int dd = 0; dd < 4; ++dd)
    wofs[dd] = c4 * 32 + ((scw ^ ((c4 ^ dd) & 3)) << 3) + (r & 7);

  const int L = lane & 15, kc4 = lane >> 4;
  const int dA = wave * 16 + L;
  const int dq = tid & 63, q4 = tid >> 6;
  const int Fks = (q4 ^ dq) & 3;
  const int ksbase = (dq * 4 + q4) * 32;

  for (int st = 0; st < 32; ++st) {
    const int s0 = st * 128;
    __syncthreads();  // prior tile's reads done before overwrite
    {
      const unsigned short* krow = kb + (size_t)(s0 + r) * 64 + hf * 32;
      const unsigned short* vrow = vb + (size_t)(s0 + r) * 64 + hf * 32;
      bf16x8 kk[4], vv[4];
#pragma unroll
      for (int g = 0; g < 4; ++g) {
        kk[g] = *(const bf16x8*)(krow + g * 8);
        vv[g] = *(const bf16x8*)(vrow + g * 8);
      }
#pragma unroll
      for (int g = 0; g < 4; ++g)
#pragma unroll
        for (int i = 0; i < 8; ++i) {
          const int d = hf * 32 + g * 8 + i;
          const int a = d * 128 + wofs[d & 3];
          kl[a] = (unsigned short)kk[g][i];
          vl[a] = (unsigned short)vv[g][i];
        }
    }
    __syncthreads();
    // ksum partial
#pragma unroll
    for (int scc = 0; scc < 4; ++scc) {
      const bf16x8 t8 = *(const bf16x8*)&kl[ksbase + ((scc ^ Fks) << 3)];
#pragma unroll
      for (int i = 0; i < 8; ++i) ks += bf2f((unsigned short)t8[i]);
    }
    // MFMA: D[d][e] += sum_s k[s,d] v[s,e]
#pragma unroll
    for (int ksl = 0; ksl < 4; ++ksl) {
      const int physA = kc4 ^ ((ksl ^ dA) & 3);
      const bf16x8 aF = *(const bf16x8*)&kl[(dA * 4 + ksl) * 32 + physA * 8];
#pragma unroll
      for (int n = 0; n < 4; ++n) {
        const int e = n * 16 + L;
        const int physB = kc4 ^ ((ksl ^ e) & 3);
        const bf16x8 bF = *(const bf16x8*)&vl[(e * 4 + ksl) * 32 + physB * 8];
        acc[n] = __builtin_amdgcn_mfma_f32_16x16x32_bf16(aF, bF, acc[n], 0, 0, 0);
      }
    }
  }
  red[tid] = ks;
  __syncthreads();
  if (tid < 64) ksum[bh * 64 + tid] = red[tid] + red[64 + tid] + red[128 + tid] + red[192 + tid];
#pragma unroll
  for (int n = 0; n < 4; ++n)
#pragma unroll
    for (int j = 0; j < 4; ++j) {
      const int d = wave * 16 + (lane >> 4) * 4 + j;
      const int e = n * 16 + (lane & 15);
      kvT[bh * 4096 + e * 64 + d] = acc[n][j];
    }
}

// ---------------------------------------------------------------------------
// attn out: out[s,e] = z_s * sum_d q[s,d] kv[d,e]; z_s = 1/sum_d q[s,d] ksum[d]
// Block order reversed (LIFO handoff of q).
// ---------------------------------------------------------------------------
__global__ __launch_bounds__(256) void attn_out_kernel(const unsigned short* __restrict__ q,
                                                       const float* __restrict__ kvT,
                                                       const float* __restrict__ ksum,
                                                       unsigned short* __restrict__ attnout) {
  __shared__ float kvl[4096];
  __shared__ float ksl[64];
  __shared__ float zl[4 * 64];
  const int tid = threadIdx.x;
  const int lane = tid & 63, wave = tid >> 6;
  const int bidx = gridDim.x - 1 - blockIdx.x;
  const int bh = bidx >> 2;
  const int chunk = bidx & 3;
  const int b = bh / 12, h = bh % 12;
  const float* kvb = kvT + (size_t)bh * 4096;
  for (int i = tid; i < 4096; i += 256) kvl[i] = kvb[i];
  if (tid < 64) ksl[tid] = ksum[(size_t)bh * 64 + tid];
  __syncthreads();

  const int kh = (lane >> 4) * 8;
  bf16x8 bF[4], ksF;
#pragma unroll
  for (int n = 0; n < 4; ++n) {
    bf16x8 t;
#pragma unroll
    for (int j = 0; j < 8; ++j)
      t[j] = (short)f2bf(kvl[((lane & 15) + 16 * n) * 64 + kh + j]);
    bF[n] = t;
  }
  {
    bf16x8 t;
#pragma unroll
    for (int j = 0; j < 8; ++j)
      t[j] = ((lane & 15) == 0) ? (short)f2bf(ksl[kh + j]) : (short)0;
    ksF = t;
  }
  const unsigned short* qb = q + (size_t)bh * 4096 * 64;

  for (int st = 0; st < 4; ++st) {
    const int s0 = chunk * 1024 + wave * 256 + st * 64;
    bf16x8 aF[4];
#pragma unroll
    for (int m = 0; m < 4; ++m)
      aF[m] = *(const bf16x8*)&qb[(size_t)(s0 + (lane & 15) + 16 * m) * 64 + kh];
    f32x4 acc[4][4];
    f32x4 dacc[4];
#pragma unroll
    for (int m = 0; m < 4; ++m) {
      dacc[m] = f32x4{0.f, 0.f, 0.f, 0.f};
#pragma unroll
      for (int n = 0; n < 4; ++n) acc[m][n] = f32x4{0.f, 0.f, 0.f, 0.f};
    }
#pragma unroll
    for (int m = 0; m < 4; ++m) {
#pragma unroll
      for (int n = 0; n < 4; ++n)
        acc[m][n] = __builtin_amdgcn_mfma_f32_16x16x32_bf16(aF[m], bF[n], acc[m][n], 0, 0, 0);
      dacc[m] = __builtin_amdgcn_mfma_f32_16x16x32_bf16(aF[m], ksF, dacc[m], 0, 0, 0);
    }
    if ((lane & 15) == 0) {
#pragma unroll
      for (int m = 0; m < 4; ++m)
#pragma unroll
        for (int j = 0; j < 4; ++j)
          zl[wave * 64 + m * 16 + (lane >> 4) * 4 + j] = 1.0f / dacc[m][j];
    }
    __syncthreads();
#pragma unroll
    for (int m = 0; m < 4; ++m)
#pragma unroll
      for (int n = 0; n < 4; ++n)
#pragma unroll
        for (int j = 0; j < 4; ++j) {
          const int sl = m * 16 + (lane >> 4) * 4 + j;
          const int s = s0 + sl;
          const float val = acc[m][n][j] * zl[wave * 64 + sl];
          const int e = n * 16 + (lane & 15);
          attnout[((size_t)b * 4096 + s) * 768 + h * 64 + e] = f2bf(val);
        }
    __syncthreads();
  }
}

// ---------------------------------------------------------------------------
extern "C" void kernel_launch(void* const* d_in, const int* in_sizes, int n_in,
                              void* d_out, int out_size, void* d_ws, size_t ws_size,
                              hipStream_t stream) {
  const float* x = (const float*)d_in[0];
  const float* qkv_w = (const float*)d_in[1];
  const float* qkv_b = (const float*)d_in[2];
  const float* proj_w = (const float*)d_in[3];
  const float* proj_b = (const float*)d_in[4];
  const float* fc1_w = (const float*)d_in[5];
  const float* fc1_b = (const float*)d_in[6];
  const float* fc2_w = (const float*)d_in[7];
  const float* fc2_b = (const float*)d_in[8];
  const float* ln1_w = (const float*)d_in[9];
  const float* ln1_b = (const float*)d_in[10];
  const float* ln2_w = (const float*)d_in[11];
  const float* ln2_b = (const float*)d_in[12];
  float* out = (float*)d_out;

  char* ws = (char*)d_ws;
  const size_t PL = (size_t)65536 * 768 * 2;  // one bf16 plane
  unsigned short* xn = (unsigned short*)(ws + 0 * PL);
  unsigned short* q = (unsigned short*)(ws + 1 * PL);
  unsigned short* kbuf = (unsigned short*)(ws + 2 * PL);
  unsigned short* vbuf = (unsigned short*)(ws + 3 * PL);
  unsigned short* attnout = xn;
  unsigned short* ybuf = kbuf;
  unsigned short* xn2 = (unsigned short*)(ws + 4 * PL);
  unsigned short* hbuf = (unsigned short*)(ws + 0 * PL);  // planes 0-3
  size_t off = 5 * PL;
  float* kvT = (float*)(ws + off); off += (size_t)192 * 4096 * 4;
  float* ksum = (float*)(ws + off); off += (size_t)192 * 64 * 4;
  unsigned short* qkvWt = (unsigned short*)(ws + off); off += (size_t)2304 * 768 * 2;
  unsigned short* projWt = (unsigned short*)(ws + off); off += (size_t)768 * 768 * 2;
  unsigned short* fc1Wt = (unsigned short*)(ws + off); off += (size_t)3072 * 768 * 2;
  unsigned short* fc2Wt = (unsigned short*)(ws + off); off += (size_t)768 * 3072 * 2;

  // 1. weight transpose+cast
  wt_kernel<<<dim3(72, 24), 256, 0, stream>>>(qkv_w, qkvWt, 768, 2304);
  wt_kernel<<<dim3(24, 24), 256, 0, stream>>>(proj_w, projWt, 768, 768);
  wt_kernel<<<dim3(96, 24), 256, 0, stream>>>(fc1_w, fc1Wt, 768, 3072);
  wt_kernel<<<dim3(24, 96), 256, 0, stream>>>(fc2_w, fc2Wt, 3072, 768);
  // 2. LN1
  ln_kernel<<<16384, 256, 0, stream>>>(x, ln1_w, ln1_b, xn);
  // 3. qkv GEMM: q,k (elu+1), v all stored [bh][s][d]
  gemm_k<2><<<dim3(9, 512), 512, 0, stream>>>(xn, qkvWt, qkv_b, 2304, 768, q, kbuf, vbuf, nullptr);
  // 4. kv + ksum (transpose inside)
  kv_kernel<<<192, 256, 0, stream>>>(kbuf, vbuf, kvT, ksum);
  // 5. attention out
  attn_out_kernel<<<768, 256, 0, stream>>>(q, kvT, ksum, attnout);
  // 6. proj GEMM -> y
  gemm_k<0><<<dim3(3, 512), 512, 0, stream>>>(attnout, projWt, proj_b, 768, 768, ybuf, nullptr,
                                              nullptr, nullptr);
  // 7. residual + LN2 (x2 lives in d_out)
  fuse_kernel<<<16384, 256, 0, stream>>>(x, ybuf, ln2_w, ln2_b, out, xn2);
  // 8. fc1 + gelu (fast tanh-form)
  gemm_k<1><<<dim3(12, 512), 512, 0, stream>>>(xn2, fc1Wt, fc1_b, 3072, 768, hbuf, nullptr,
                                               nullptr, nullptr);
  // 9. fc2 + residual RMW into out (reversed block order)
  gemm_k<3><<<dim3(3, 512), 512, 0, stream>>>(hbuf, fc2Wt, fc2_b, 768, 3072, nullptr, nullptr,
                                              nullptr, out);
  (void)in_sizes; (void)n_in; (void)out_size; (void)ws_size;
}